// Round 4
// baseline (39.223 us; speedup 1.0000x reference)
//
#include <hip/hip_runtime.h>

static constexpr float INV_SQRT2 = 0.70710678118654752f;
static constexpr float INV_SQRT3 = 0.57735026918962576f;
static constexpr float SQRT2     = 1.41421356237309505f;
static constexpr float INV_SQRT6 = 0.40824829046386302f;

static constexpr int W_GRAPHS = 8;  // graphs per wave

// Kernel 1: boundary finder. bnd[g] = first node index with batch[i] >= g,
// for g in [0, n_graphs]; bnd[n_graphs] = n. batch is sorted, so each bnd
// entry has exactly one writer (no atomics, every entry written every call).
__global__ __launch_bounds__(256) void find_bounds(
    const int* __restrict__ batch,
    int*       __restrict__ bnd,
    int n, int n_graphs)
{
    const int i = blockIdx.x * blockDim.x + threadIdx.x;
    if (i >= n) return;
    const int cur  = batch[i];
    const int prev = (i == 0) ? -1 : batch[i - 1];
    for (int g = prev + 1; g <= cur; ++g) bnd[g] = i;
    if (i == n - 1) {
        for (int g = cur + 1; g <= n_graphs; ++g) bnd[g] = n;
    }
}

// Kernel 2: each wave owns W_GRAPHS whole graphs and writes out[g] directly.
// No atomics, no workspace accumulators, batch[] never read here.
__global__ __launch_bounds__(256) void e3nn_graphs(
    const int*   __restrict__ z,
    const float* __restrict__ pos,
    const int*   __restrict__ bnd,
    const float* __restrict__ w_tp,
    const float* __restrict__ fc_w,
    const float* __restrict__ fc_b,
    float*       __restrict__ out,
    int n_graphs)
{
    const int lane = threadIdx.x & 63;
    const int wave = (blockIdx.x * blockDim.x + threadIdx.x) >> 6;
    const int g0   = wave * W_GRAPHS;
    if (g0 >= n_graphs) return;

    // uniform weights (scalar loads)
    const float wA0 = w_tp[0], wA1 = w_tp[1];
    const float wB0 = w_tp[2], wB1 = w_tp[3];
    const float c0  = (w_tp[4] + w_tp[6]) * INV_SQRT2;
    const float c1  = (w_tp[5] + w_tp[7]) * INV_SQRT2;
    const float wE  = w_tp[8];
    float fw[13];
#pragma unroll
    for (int j = 0; j < 13; ++j) fw[j] = fc_w[j];
    const float fb = fc_b[0];

    // lanes 0..W_GRAPHS hold the 9 boundary values for this wave
    int bval = 0;
    {
        int idx = g0 + lane;
        if (lane <= W_GRAPHS && idx <= n_graphs) bval = bnd[idx];
    }

#pragma unroll 1
    for (int g = 0; g < W_GRAPHS; ++g) {
        if (g0 + g >= n_graphs) break;
        const int s = __shfl(bval, g);
        const int e = __shfl(bval, g + 1);

        float part = 0.f;
#pragma unroll 1
        for (int base = s; base < e; base += 64) {
            const int i = base + lane;
            if (i < e) {
                const float sc = (float)z[i];
                const float v0 = pos[i * 3 + 0];
                const float v1 = pos[i * 3 + 1];
                const float v2 = pos[i * 3 + 2];

                const float ss   = sc * sc;
                const float dot3 = (v0 * v0 + v1 * v1 + v2 * v2) * INV_SQRT3;

                const float x0 = (ss * wA0 + dot3 * wB0) * INV_SQRT2;
                const float x1 = (ss * wA1 + dot3 * wB1) * INV_SQRT2;

                const float sv0 = sc * v0, sv1 = sc * v1, sv2 = sc * v2;
                const float x2 = sv0 * c0, x3 = sv1 * c0, x4 = sv2 * c0;
                const float x5 = sv0 * c1, x6 = sv1 * c1, x7 = sv2 * c1;

                const float x8  = wE * (SQRT2 * v0 * v1);
                const float x9  = wE * (SQRT2 * v1 * v2);
                const float x10 = wE * (SQRT2 * v0 * v2);
                const float x11 = wE * (INV_SQRT2 * (v0 * v0 - v1 * v1));
                const float x12 = wE * (INV_SQRT6 * (2.f * v2 * v2 - v0 * v0 - v1 * v1));

                float acc = fb;
                acc += fmaxf(x0,  0.f) * fw[0];
                acc += fmaxf(x1,  0.f) * fw[1];
                acc += fmaxf(x2,  0.f) * fw[2];
                acc += fmaxf(x3,  0.f) * fw[3];
                acc += fmaxf(x4,  0.f) * fw[4];
                acc += fmaxf(x5,  0.f) * fw[5];
                acc += fmaxf(x6,  0.f) * fw[6];
                acc += fmaxf(x7,  0.f) * fw[7];
                acc += fmaxf(x8,  0.f) * fw[8];
                acc += fmaxf(x9,  0.f) * fw[9];
                acc += fmaxf(x10, 0.f) * fw[10];
                acc += fmaxf(x11, 0.f) * fw[11];
                acc += fmaxf(x12, 0.f) * fw[12];
                part += tanhf(acc);
            }
        }

        // butterfly reduce across the wave
#pragma unroll
        for (int off = 32; off >= 1; off >>= 1) part += __shfl_xor(part, off);

        if (lane == 0) {
            const float cnt = (float)(e - s);
            out[g0 + g] = part / fmaxf(cnt, 1.0f);
        }
    }
}

extern "C" void kernel_launch(void* const* d_in, const int* in_sizes, int n_in,
                              void* d_out, int out_size, void* d_ws, size_t ws_size,
                              hipStream_t stream) {
    const int*   z     = (const int*)d_in[0];
    const float* pos   = (const float*)d_in[1];
    const int*   batch = (const int*)d_in[2];
    const float* w_tp  = (const float*)d_in[3];
    const float* fc_w  = (const float*)d_in[4];
    const float* fc_b  = (const float*)d_in[5];

    float* out = (float*)d_out;
    int*   bnd = (int*)d_ws;               // n_graphs + 1 ints
    const int n        = in_sizes[0];
    const int n_graphs = out_size;

    const int b1 = (n + 255) / 256;
    find_bounds<<<b1, 256, 0, stream>>>(batch, bnd, n, n_graphs);

    const int waves = (n_graphs + W_GRAPHS - 1) / W_GRAPHS;
    const int b2    = (waves * 64 + 255) / 256;
    e3nn_graphs<<<b2, 256, 0, stream>>>(z, pos, bnd, w_tp, fc_w, fc_b,
                                        out, n_graphs);
}

// Round 6
// 32.319 us; speedup vs baseline: 1.2136x; 1.2136x over previous
//
#include <hip/hip_runtime.h>

static constexpr float INV_SQRT2 = 0.70710678118654752f;
static constexpr float INV_SQRT3 = 0.57735026918962576f;
static constexpr float SQRT2     = 1.41421356237309505f;
static constexpr float INV_SQRT6 = 0.40824829046386302f;

static constexpr int W_GRAPHS = 8;  // graphs per wave

// Kernel 1: bnd[g] = first node index with batch[i] >= g, g in [0, n_graphs];
// bnd[n_graphs] = n. batch sorted -> each entry has exactly one writer.
__global__ __launch_bounds__(256) void find_bounds(
    const int* __restrict__ batch,
    int*       __restrict__ bnd,
    int n, int n_graphs)
{
    const int i = blockIdx.x * blockDim.x + threadIdx.x;
    if (i >= n) return;
    const int cur  = batch[i];
    const int prev = (i == 0) ? -1 : batch[i - 1];
    for (int g = prev + 1; g <= cur; ++g) bnd[g] = i;
    if (i == n - 1) {
        for (int g = cur + 1; g <= n_graphs; ++g) bnd[g] = n;
    }
}

// Kernel 2: each wave owns 8 graphs and walks their UNION node range
// [bnd[g0], bnd[g0+8]) contiguously (coalesced, ~96% lane utilization).
// Per-node graph id derived from the 7 interior boundaries; accumulate
// into 8 named registers via compare-select; one reduction in epilogue.
// NOTE: all __shfl ops are in CONVERGED code (divergent-lane shuffle reads
// are undefined on gfx9 — that was round 5's bug).
__global__ __launch_bounds__(256) void e3nn_g8(
    const int*   __restrict__ z,
    const float* __restrict__ pos,
    const int*   __restrict__ bnd,
    const float* __restrict__ w_tp,
    const float* __restrict__ fc_w,
    const float* __restrict__ fc_b,
    float*       __restrict__ out,
    int n_graphs)
{
    const int lane = threadIdx.x & 63;
    const int wave = (blockIdx.x * blockDim.x + threadIdx.x) >> 6;
    const int g0   = wave * W_GRAPHS;
    if (g0 >= n_graphs) return;

    // uniform weights (scalar loads)
    const float wA0 = w_tp[0], wA1 = w_tp[1];
    const float wB0 = w_tp[2], wB1 = w_tp[3];
    const float c0  = (w_tp[4] + w_tp[6]) * INV_SQRT2;
    const float c1  = (w_tp[5] + w_tp[7]) * INV_SQRT2;
    const float wE  = w_tp[8];
    float fw[13];
#pragma unroll
    for (int j = 0; j < 13; ++j) fw[j] = fc_w[j];
    const float fb = fc_b[0];

    int bval = 0;
    {
        const int idx = g0 + lane;
        if (lane <= W_GRAPHS && idx <= n_graphs) bval = bnd[idx];
    }
    // converged: all lanes participate
    const int nb = __shfl_down(bval, 1);   // lane l: bnd[g0+l+1] (l<=7 valid)
    const int B0 = __shfl(bval, 0), B1 = __shfl(bval, 1);
    const int B2 = __shfl(bval, 2), B3 = __shfl(bval, 3);
    const int B4 = __shfl(bval, 4), B5 = __shfl(bval, 5);
    const int B6 = __shfl(bval, 6), B7 = __shfl(bval, 7);
    const int B8 = __shfl(bval, 8);

    float a0 = 0.f, a1 = 0.f, a2 = 0.f, a3 = 0.f;
    float a4 = 0.f, a5 = 0.f, a6 = 0.f, a7 = 0.f;

#pragma unroll 1
    for (int base = B0; base < B8; base += 64) {
        const int i = base + lane;
        if (i < B8) {
            const float sc = (float)z[i];
            const float v0 = pos[i * 3 + 0];
            const float v1 = pos[i * 3 + 1];
            const float v2 = pos[i * 3 + 2];

            const float ss   = sc * sc;
            const float dot3 = (v0 * v0 + v1 * v1 + v2 * v2) * INV_SQRT3;

            const float x0 = (ss * wA0 + dot3 * wB0) * INV_SQRT2;
            const float x1 = (ss * wA1 + dot3 * wB1) * INV_SQRT2;

            const float sv0 = sc * v0, sv1 = sc * v1, sv2 = sc * v2;
            const float x2 = sv0 * c0, x3 = sv1 * c0, x4 = sv2 * c0;
            const float x5 = sv0 * c1, x6 = sv1 * c1, x7 = sv2 * c1;

            const float x8  = wE * (SQRT2 * v0 * v1);
            const float x9  = wE * (SQRT2 * v1 * v2);
            const float x10 = wE * (SQRT2 * v0 * v2);
            const float x11 = wE * (INV_SQRT2 * (v0 * v0 - v1 * v1));
            const float x12 = wE * (INV_SQRT6 * (2.f * v2 * v2 - v0 * v0 - v1 * v1));

            float acc = fb;
            acc += fmaxf(x0,  0.f) * fw[0];
            acc += fmaxf(x1,  0.f) * fw[1];
            acc += fmaxf(x2,  0.f) * fw[2];
            acc += fmaxf(x3,  0.f) * fw[3];
            acc += fmaxf(x4,  0.f) * fw[4];
            acc += fmaxf(x5,  0.f) * fw[5];
            acc += fmaxf(x6,  0.f) * fw[6];
            acc += fmaxf(x7,  0.f) * fw[7];
            acc += fmaxf(x8,  0.f) * fw[8];
            acc += fmaxf(x9,  0.f) * fw[9];
            acc += fmaxf(x10, 0.f) * fw[10];
            acc += fmaxf(x11, 0.f) * fw[11];
            acc += fmaxf(x12, 0.f) * fw[12];
            const float y = tanhf(acc);

            const int gi = (i >= B1) + (i >= B2) + (i >= B3) + (i >= B4)
                         + (i >= B5) + (i >= B6) + (i >= B7);
            a0 += (gi == 0) ? y : 0.f;
            a1 += (gi == 1) ? y : 0.f;
            a2 += (gi == 2) ? y : 0.f;
            a3 += (gi == 3) ? y : 0.f;
            a4 += (gi == 4) ? y : 0.f;
            a5 += (gi == 5) ? y : 0.f;
            a6 += (gi == 6) ? y : 0.f;
            a7 += (gi == 7) ? y : 0.f;
        }
    }

    // one butterfly reduction per accumulator (epilogue only, converged)
#pragma unroll
    for (int off = 32; off >= 1; off >>= 1) {
        a0 += __shfl_xor(a0, off);
        a1 += __shfl_xor(a1, off);
        a2 += __shfl_xor(a2, off);
        a3 += __shfl_xor(a3, off);
        a4 += __shfl_xor(a4, off);
        a5 += __shfl_xor(a5, off);
        a6 += __shfl_xor(a6, off);
        a7 += __shfl_xor(a7, off);
    }

    // lanes 0..7 write the 8 outputs (nb computed while converged)
    if (lane < W_GRAPHS && g0 + lane < n_graphs) {
        float sel = (lane == 0) ? a0
                  : (lane == 1) ? a1
                  : (lane == 2) ? a2
                  : (lane == 3) ? a3
                  : (lane == 4) ? a4
                  : (lane == 5) ? a5
                  : (lane == 6) ? a6
                  :               a7;
        const float c = (float)(nb - bval);
        out[g0 + lane] = sel / fmaxf(c, 1.0f);
    }
}

extern "C" void kernel_launch(void* const* d_in, const int* in_sizes, int n_in,
                              void* d_out, int out_size, void* d_ws, size_t ws_size,
                              hipStream_t stream) {
    const int*   z     = (const int*)d_in[0];
    const float* pos   = (const float*)d_in[1];
    const int*   batch = (const int*)d_in[2];
    const float* w_tp  = (const float*)d_in[3];
    const float* fc_w  = (const float*)d_in[4];
    const float* fc_b  = (const float*)d_in[5];

    float* out = (float*)d_out;
    int*   bnd = (int*)d_ws;               // n_graphs + 1 ints
    const int n        = in_sizes[0];
    const int n_graphs = out_size;

    const int b1 = (n + 255) / 256;
    find_bounds<<<b1, 256, 0, stream>>>(batch, bnd, n, n_graphs);

    const int waves = (n_graphs + W_GRAPHS - 1) / W_GRAPHS;
    const int b2    = (waves * 64 + 255) / 256;
    e3nn_g8<<<b2, 256, 0, stream>>>(z, pos, bnd, w_tp, fc_w, fc_b,
                                    out, n_graphs);
}

// Round 7
// 31.799 us; speedup vs baseline: 1.2334x; 1.0164x over previous
//
#include <hip/hip_runtime.h>

static constexpr float INV_SQRT2 = 0.70710678118654752f;
static constexpr float INV_SQRT3 = 0.57735026918962576f;
static constexpr float SQRT2     = 1.41421356237309505f;
static constexpr float INV_SQRT6 = 0.40824829046386302f;

static constexpr int W_GRAPHS = 8;  // graphs per wave

// Single fused kernel. Each wave owns 8 graphs; it finds its 9 segment
// boundaries itself via branchless lower_bound over the sorted batch array
// (22 probes for n=2^22; lanes share probes via broadcast), then walks the
// union node range [B0,B8) contiguously (coalesced, ~96% lane utilization),
// routing each node's tanh output into 8 named per-lane accumulators by
// compare-select, one butterfly reduction in the epilogue, lanes 0..7 write
// out[g] = sum/count directly. No workspace, no atomics, no second dispatch.
__global__ __launch_bounds__(256) void e3nn_fused(
    const int*   __restrict__ z,
    const float* __restrict__ pos,
    const int*   __restrict__ batch,
    const float* __restrict__ w_tp,
    const float* __restrict__ fc_w,
    const float* __restrict__ fc_b,
    float*       __restrict__ out,
    int n, int n_graphs)
{
    const int lane = threadIdx.x & 63;
    const int wave = (blockIdx.x * blockDim.x + threadIdx.x) >> 6;
    const int g0   = wave * W_GRAPHS;
    if (g0 >= n_graphs) return;

    // uniform weights (scalar loads)
    const float wA0 = w_tp[0], wA1 = w_tp[1];
    const float wB0 = w_tp[2], wB1 = w_tp[3];
    const float c0  = (w_tp[4] + w_tp[6]) * INV_SQRT2;
    const float c1  = (w_tp[5] + w_tp[7]) * INV_SQRT2;
    const float wE  = w_tp[8];
    float fw[13];
#pragma unroll
    for (int j = 0; j < 13; ++j) fw[j] = fc_w[j];
    const float fb = fc_b[0];

    // --- per-lane lower_bound(batch, target): bval = first i with batch[i] >= target.
    // Lanes 0..8 use target g0+lane; lanes 9..63 clamp (harmless duplicates).
    const int tl     = (lane < W_GRAPHS) ? lane : W_GRAPHS;
    const int target = g0 + tl;
    // round n up to a power of two for the fixed-step descent
    unsigned p2 = 1;
    while (p2 < (unsigned)n) p2 <<= 1;
    int bval = 0;
    for (unsigned step = p2 >> 1; step > 0; step >>= 1) {
        const unsigned cand = (unsigned)bval + step;
        if (cand <= (unsigned)n && batch[cand - 1] < target) bval = (int)cand;
    }

    // converged shuffles: distribute boundaries
    const int nb = __shfl_down(bval, 1);   // lane l: bnd[g0+l+1] (valid l<=7)
    const int B0 = __shfl(bval, 0), B1 = __shfl(bval, 1);
    const int B2 = __shfl(bval, 2), B3 = __shfl(bval, 3);
    const int B4 = __shfl(bval, 4), B5 = __shfl(bval, 5);
    const int B6 = __shfl(bval, 6), B7 = __shfl(bval, 7);
    const int B8 = __shfl(bval, 8);

    float a0 = 0.f, a1 = 0.f, a2 = 0.f, a3 = 0.f;
    float a4 = 0.f, a5 = 0.f, a6 = 0.f, a7 = 0.f;

#pragma unroll 1
    for (int base = B0; base < B8; base += 64) {
        const int i = base + lane;
        if (i < B8) {
            const float sc = (float)z[i];
            const float v0 = pos[i * 3 + 0];
            const float v1 = pos[i * 3 + 1];
            const float v2 = pos[i * 3 + 2];

            const float ss   = sc * sc;
            const float dot3 = (v0 * v0 + v1 * v1 + v2 * v2) * INV_SQRT3;

            const float x0 = (ss * wA0 + dot3 * wB0) * INV_SQRT2;
            const float x1 = (ss * wA1 + dot3 * wB1) * INV_SQRT2;

            const float sv0 = sc * v0, sv1 = sc * v1, sv2 = sc * v2;
            const float x2 = sv0 * c0, x3 = sv1 * c0, x4 = sv2 * c0;
            const float x5 = sv0 * c1, x6 = sv1 * c1, x7 = sv2 * c1;

            const float x8  = wE * (SQRT2 * v0 * v1);
            const float x9  = wE * (SQRT2 * v1 * v2);
            const float x10 = wE * (SQRT2 * v0 * v2);
            const float x11 = wE * (INV_SQRT2 * (v0 * v0 - v1 * v1));
            const float x12 = wE * (INV_SQRT6 * (2.f * v2 * v2 - v0 * v0 - v1 * v1));

            float acc = fb;
            acc += fmaxf(x0,  0.f) * fw[0];
            acc += fmaxf(x1,  0.f) * fw[1];
            acc += fmaxf(x2,  0.f) * fw[2];
            acc += fmaxf(x3,  0.f) * fw[3];
            acc += fmaxf(x4,  0.f) * fw[4];
            acc += fmaxf(x5,  0.f) * fw[5];
            acc += fmaxf(x6,  0.f) * fw[6];
            acc += fmaxf(x7,  0.f) * fw[7];
            acc += fmaxf(x8,  0.f) * fw[8];
            acc += fmaxf(x9,  0.f) * fw[9];
            acc += fmaxf(x10, 0.f) * fw[10];
            acc += fmaxf(x11, 0.f) * fw[11];
            acc += fmaxf(x12, 0.f) * fw[12];
            const float y = tanhf(acc);

            const int gi = (i >= B1) + (i >= B2) + (i >= B3) + (i >= B4)
                         + (i >= B5) + (i >= B6) + (i >= B7);
            a0 += (gi == 0) ? y : 0.f;
            a1 += (gi == 1) ? y : 0.f;
            a2 += (gi == 2) ? y : 0.f;
            a3 += (gi == 3) ? y : 0.f;
            a4 += (gi == 4) ? y : 0.f;
            a5 += (gi == 5) ? y : 0.f;
            a6 += (gi == 6) ? y : 0.f;
            a7 += (gi == 7) ? y : 0.f;
        }
    }

    // one butterfly reduction per accumulator (epilogue only, converged)
#pragma unroll
    for (int off = 32; off >= 1; off >>= 1) {
        a0 += __shfl_xor(a0, off);
        a1 += __shfl_xor(a1, off);
        a2 += __shfl_xor(a2, off);
        a3 += __shfl_xor(a3, off);
        a4 += __shfl_xor(a4, off);
        a5 += __shfl_xor(a5, off);
        a6 += __shfl_xor(a6, off);
        a7 += __shfl_xor(a7, off);
    }

    // lanes 0..7 write the 8 outputs (nb computed while converged)
    if (lane < W_GRAPHS && g0 + lane < n_graphs) {
        float sel = (lane == 0) ? a0
                  : (lane == 1) ? a1
                  : (lane == 2) ? a2
                  : (lane == 3) ? a3
                  : (lane == 4) ? a4
                  : (lane == 5) ? a5
                  : (lane == 6) ? a6
                  :               a7;
        const float c = (float)(nb - bval);
        out[g0 + lane] = sel / fmaxf(c, 1.0f);
    }
}

extern "C" void kernel_launch(void* const* d_in, const int* in_sizes, int n_in,
                              void* d_out, int out_size, void* d_ws, size_t ws_size,
                              hipStream_t stream) {
    const int*   z     = (const int*)d_in[0];
    const float* pos   = (const float*)d_in[1];
    const int*   batch = (const int*)d_in[2];
    const float* w_tp  = (const float*)d_in[3];
    const float* fc_w  = (const float*)d_in[4];
    const float* fc_b  = (const float*)d_in[5];

    float* out = (float*)d_out;
    const int n        = in_sizes[0];
    const int n_graphs = out_size;

    const int waves = (n_graphs + W_GRAPHS - 1) / W_GRAPHS;
    const int blocks = (waves * 64 + 255) / 256;
    e3nn_fused<<<blocks, 256, 0, stream>>>(z, pos, batch, w_tp, fc_w, fc_b,
                                           out, n, n_graphs);
}

// Round 8
// 27.610 us; speedup vs baseline: 1.4206x; 1.1518x over previous
//
#include <hip/hip_runtime.h>

static constexpr float INV_SQRT2 = 0.70710678118654752f;
static constexpr float INV_SQRT3 = 0.57735026918962576f;
static constexpr float SQRT2     = 1.41421356237309505f;
static constexpr float INV_SQRT6 = 0.40824829046386302f;

static constexpr int W_GRAPHS = 8;  // graphs per wave

// branchless fast tanh: 1 - 2/(exp(2x)+1); exact at +/-inf, err ~1e-7
__device__ __forceinline__ float fast_tanh(float x) {
    const float e = __builtin_amdgcn_exp2f(x * 2.8853900817779268f); // 2*log2(e)
    const float r = __builtin_amdgcn_rcpf(e + 1.0f);
    return fmaf(-2.0f, r, 1.0f);
}

// sign-gated coefficient: relu(t*k)*fw == t * (t>0 ? pos_part : neg_part)
__device__ __forceinline__ float gate_p(float k, float fw) { return k > 0.f ? k * fw : 0.f; }
__device__ __forceinline__ float gate_n(float k, float fw) { return k < 0.f ? k * fw : 0.f; }

// Single fused kernel. Each wave owns 8 graphs; finds its 9 boundaries via
// branchless lower_bound on the sorted batch array, walks the union node
// range contiguously (coalesced), routes each node's tanh output into 8
// named accumulators via range masks, one butterfly in the epilogue.
__global__ __launch_bounds__(256) void e3nn_fused(
    const int*   __restrict__ z,
    const float* __restrict__ pos,
    const int*   __restrict__ batch,
    const float* __restrict__ w_tp,
    const float* __restrict__ fc_w,
    const float* __restrict__ fc_b,
    float*       __restrict__ out,
    int n, int n_graphs)
{
    const int lane = threadIdx.x & 63;
    const int wave = (blockIdx.x * blockDim.x + threadIdx.x) >> 6;
    const int g0   = wave * W_GRAPHS;
    if (g0 >= n_graphs) return;

    // ---- uniform weight prep (once per wave) ----
    const float kA0 = w_tp[0] * INV_SQRT2;
    const float kA1 = w_tp[1] * INV_SQRT2;
    const float kB0 = w_tp[2] * (INV_SQRT3 * INV_SQRT2);
    const float kB1 = w_tp[3] * (INV_SQRT3 * INV_SQRT2);
    const float c0  = (w_tp[4] + w_tp[6]) * INV_SQRT2;
    const float c1  = (w_tp[5] + w_tp[7]) * INV_SQRT2;
    const float wE  = w_tp[8];
    const float fw0 = fc_w[0], fw1 = fc_w[1];
    const float fb  = fc_b[0];

    // sv channels: relu(sv*c0)*fw[2+i] + relu(sv*c1)*fw[5+i]
    const float P0 = gate_p(c0, fc_w[2]) + gate_p(c1, fc_w[5]);
    const float N0 = gate_n(c0, fc_w[2]) + gate_n(c1, fc_w[5]);
    const float P1 = gate_p(c0, fc_w[3]) + gate_p(c1, fc_w[6]);
    const float N1 = gate_n(c0, fc_w[3]) + gate_n(c1, fc_w[6]);
    const float P2 = gate_p(c0, fc_w[4]) + gate_p(c1, fc_w[7]);
    const float N2 = gate_n(c0, fc_w[4]) + gate_n(c1, fc_w[7]);
    // quad channels
    const float k8  = wE * SQRT2,     k11 = wE * INV_SQRT2, k12 = wE * INV_SQRT6;
    const float P8  = gate_p(k8,  fc_w[8]),  N8  = gate_n(k8,  fc_w[8]);
    const float P9  = gate_p(k8,  fc_w[9]),  N9  = gate_n(k8,  fc_w[9]);
    const float P10 = gate_p(k8,  fc_w[10]), N10 = gate_n(k8,  fc_w[10]);
    const float P11 = gate_p(k11, fc_w[11]), N11 = gate_n(k11, fc_w[11]);
    const float P12 = gate_p(k12, fc_w[12]), N12 = gate_n(k12, fc_w[12]);

    // ---- per-lane lower_bound(batch, g0 + min(lane,8)) ----
    const int tl     = (lane < W_GRAPHS) ? lane : W_GRAPHS;
    const int target = g0 + tl;
    unsigned p2 = 1;
    while (p2 < (unsigned)n) p2 <<= 1;
    int bval = 0;
    for (unsigned step = p2 >> 1; step > 0; step >>= 1) {
        const unsigned cand = (unsigned)bval + step;
        if (cand <= (unsigned)n && batch[cand - 1] < target) bval = (int)cand;
    }

    // converged shuffles: distribute boundaries
    const int nb = __shfl_down(bval, 1);   // lane l: bnd[g0+l+1] (valid l<=7)
    const int B0 = __shfl(bval, 0), B1 = __shfl(bval, 1);
    const int B2 = __shfl(bval, 2), B3 = __shfl(bval, 3);
    const int B4 = __shfl(bval, 4), B5 = __shfl(bval, 5);
    const int B6 = __shfl(bval, 6), B7 = __shfl(bval, 7);
    const int B8 = __shfl(bval, 8);

    float a0 = 0.f, a1 = 0.f, a2 = 0.f, a3 = 0.f;
    float a4 = 0.f, a5 = 0.f, a6 = 0.f, a7 = 0.f;

#pragma unroll 1
    for (int base = B0; base < B8; base += 64) {
        const int i = base + lane;
        if (i < B8) {
            const float sc = (float)z[i];
            const float v0 = pos[i * 3 + 0];
            const float v1 = pos[i * 3 + 1];
            const float v2 = pos[i * 3 + 2];

            const float v00 = v0 * v0, v11 = v1 * v1, v22 = v2 * v2;
            const float ss  = sc * sc;
            const float dr  = v00 + v11 + v22;

            float acc = fb;
            const float x0 = fmaf(ss, kA0, dr * kB0);
            const float x1 = fmaf(ss, kA1, dr * kB1);
            acc = fmaf(fmaxf(x0, 0.f), fw0, acc);
            acc = fmaf(fmaxf(x1, 0.f), fw1, acc);

            const float sv0 = sc * v0, sv1 = sc * v1, sv2 = sc * v2;
            acc = fmaf(sv0, (sv0 > 0.f ? P0 : N0), acc);
            acc = fmaf(sv1, (sv1 > 0.f ? P1 : N1), acc);
            acc = fmaf(sv2, (sv2 > 0.f ? P2 : N2), acc);

            const float t8 = v0 * v1, t9 = v1 * v2, t10 = v0 * v2;
            acc = fmaf(t8,  (t8  > 0.f ? P8  : N8 ), acc);
            acc = fmaf(t9,  (t9  > 0.f ? P9  : N9 ), acc);
            acc = fmaf(t10, (t10 > 0.f ? P10 : N10), acc);

            const float t11 = v00 - v11;
            acc = fmaf(t11, (t11 > 0.f ? P11 : N11), acc);
            const float t12 = (v22 - v00) + (v22 - v11);
            acc = fmaf(t12, (t12 > 0.f ? P12 : N12), acc);

            const float y = fast_tanh(acc);

            // range-mask routing (7 reusable compares, 8 select-adds)
            const bool ge1 = i >= B1, ge2 = i >= B2, ge3 = i >= B3;
            const bool ge4 = i >= B4, ge5 = i >= B5, ge6 = i >= B6;
            const bool ge7 = i >= B7;
            a0 += (!ge1)        ? y : 0.f;
            a1 += (ge1 && !ge2) ? y : 0.f;
            a2 += (ge2 && !ge3) ? y : 0.f;
            a3 += (ge3 && !ge4) ? y : 0.f;
            a4 += (ge4 && !ge5) ? y : 0.f;
            a5 += (ge5 && !ge6) ? y : 0.f;
            a6 += (ge6 && !ge7) ? y : 0.f;
            a7 += (ge7)         ? y : 0.f;
        }
    }

    // one butterfly reduction per accumulator (epilogue only, converged)
#pragma unroll
    for (int off = 32; off >= 1; off >>= 1) {
        a0 += __shfl_xor(a0, off);
        a1 += __shfl_xor(a1, off);
        a2 += __shfl_xor(a2, off);
        a3 += __shfl_xor(a3, off);
        a4 += __shfl_xor(a4, off);
        a5 += __shfl_xor(a5, off);
        a6 += __shfl_xor(a6, off);
        a7 += __shfl_xor(a7, off);
    }

    // lanes 0..7 write the 8 outputs (nb computed while converged)
    if (lane < W_GRAPHS && g0 + lane < n_graphs) {
        float sel = (lane == 0) ? a0
                  : (lane == 1) ? a1
                  : (lane == 2) ? a2
                  : (lane == 3) ? a3
                  : (lane == 4) ? a4
                  : (lane == 5) ? a5
                  : (lane == 6) ? a6
                  :               a7;
        const float c = (float)(nb - bval);
        out[g0 + lane] = sel / fmaxf(c, 1.0f);
    }
}

extern "C" void kernel_launch(void* const* d_in, const int* in_sizes, int n_in,
                              void* d_out, int out_size, void* d_ws, size_t ws_size,
                              hipStream_t stream) {
    const int*   z     = (const int*)d_in[0];
    const float* pos   = (const float*)d_in[1];
    const int*   batch = (const int*)d_in[2];
    const float* w_tp  = (const float*)d_in[3];
    const float* fc_w  = (const float*)d_in[4];
    const float* fc_b  = (const float*)d_in[5];

    float* out = (float*)d_out;
    const int n        = in_sizes[0];
    const int n_graphs = out_size;

    const int waves = (n_graphs + W_GRAPHS - 1) / W_GRAPHS;
    const int blocks = (waves * 64 + 255) / 256;
    e3nn_fused<<<blocks, 256, 0, stream>>>(z, pos, batch, w_tp, fc_w, fc_b,
                                           out, n, n_graphs);
}